// Round 1
// baseline (482.030 us; speedup 1.0000x reference)
//
#include <hip/hip_runtime.h>
#include <stdint.h>

// ---------- types / helpers ----------
typedef __bf16 bf16x8 __attribute__((ext_vector_type(8)));
typedef float  f32x4  __attribute__((ext_vector_type(4)));
typedef short  s16x8  __attribute__((ext_vector_type(8)));

__device__ __forceinline__ unsigned short f2bf(float f) {
  unsigned u = __builtin_bit_cast(unsigned, f);
  u += 0x7fffu + ((u >> 16) & 1u);          // RNE
  return (unsigned short)(u >> 16);
}

__device__ __forceinline__ bf16x8 ld8(const unsigned short* p) {
  return __builtin_bit_cast(bf16x8, *reinterpret_cast<const s16x8*>(p));
}

// ---------- problem constants ----------
#define BB 4
#define TT 2048
#define CC 1024
#define HH 16
#define DD 64
#define MM (BB*TT)        // 8192

// ---------- kernel 0: f32 -> bf16 convert ----------
__global__ __launch_bounds__(256) void cvt_f32_bf16(const float* __restrict__ in,
                                                    unsigned short* __restrict__ out, int n) {
  int idx = blockIdx.x * blockDim.x + threadIdx.x;
  int stride = gridDim.x * blockDim.x;
  for (int i = idx * 4; i < n; i += stride * 4) {
    float4 v = *reinterpret_cast<const float4*>(in + i);
    ushort4 o;
    o.x = f2bf(v.x); o.y = f2bf(v.y); o.z = f2bf(v.z); o.w = f2bf(v.w);
    *reinterpret_cast<ushort4*>(out + i) = o;
  }
}

// ---------- kernel 1: transpose + convert  out[n][k] = (bf16) in[k][n] ----------
__global__ __launch_bounds__(256) void transpose_cvt(const float* __restrict__ in,
                                                     unsigned short* __restrict__ out,
                                                     int K, int N) {
  __shared__ float tile[32][33];
  int kb = blockIdx.y * 32, nb = blockIdx.x * 32;
  int tx = threadIdx.x, ty = threadIdx.y;      // block (32,8)
  for (int i = 0; i < 4; i++)
    tile[ty + i*8][tx] = in[(size_t)(kb + ty + i*8) * N + nb + tx];
  __syncthreads();
  for (int i = 0; i < 4; i++)
    out[(size_t)(nb + ty + i*8) * K + kb + tx] = f2bf(tile[tx][ty + i*8]);
}

// ---------- GEMM: C[M,N] = A[M,K](bf16) * Bt[N,K](bf16) + bias ----------
// EPI 0: scatter to Q [B,H,T,D], K [B,H,T,D], V^T [B,H,D,T] as bf16
// EPI 1: fp32 out + bias
#define BMT 128
#define BNT 128
#define BKT 32
#define LDT 56   // padded leading dim (stride 112 B = 7*16B -> 2-way banks, free)

template<int EPI>
__global__ __launch_bounds__(256)
void gemm_bt(const unsigned short* __restrict__ A, const unsigned short* __restrict__ Bt,
             const float* __restrict__ bias, int K,
             unsigned short* __restrict__ qbuf, unsigned short* __restrict__ kbuf,
             unsigned short* __restrict__ vtbuf, float* __restrict__ outf)
{
  __shared__ unsigned short As[BMT * LDT];
  __shared__ unsigned short Bs[BNT * LDT];
  const int tid  = threadIdx.x;
  const int lane = tid & 63;
  const int w    = tid >> 6;
  const int wr   = w >> 1, wc = w & 1;
  const int lo   = lane & 15, hi = lane >> 4;
  const int row0 = blockIdx.x * BMT, col0 = blockIdx.y * BNT;

  f32x4 acc[4][4];
  for (int m = 0; m < 4; m++)
    for (int n = 0; n < 4; n++)
      for (int j = 0; j < 4; j++) acc[m][n][j] = 0.f;

  const int sr = tid >> 2;         // 0..63
  const int sc = (tid & 3) * 8;    // 0,8,16,24

  for (int k0 = 0; k0 < K; k0 += BKT) {
    s16x8 a0 = *reinterpret_cast<const s16x8*>(A  + (size_t)(row0 + sr)      * K + k0 + sc);
    s16x8 a1 = *reinterpret_cast<const s16x8*>(A  + (size_t)(row0 + sr + 64) * K + k0 + sc);
    s16x8 b0 = *reinterpret_cast<const s16x8*>(Bt + (size_t)(col0 + sr)      * K + k0 + sc);
    s16x8 b1 = *reinterpret_cast<const s16x8*>(Bt + (size_t)(col0 + sr + 64) * K + k0 + sc);
    *reinterpret_cast<s16x8*>(As + sr        * LDT + sc) = a0;
    *reinterpret_cast<s16x8*>(As + (sr + 64) * LDT + sc) = a1;
    *reinterpret_cast<s16x8*>(Bs + sr        * LDT + sc) = b0;
    *reinterpret_cast<s16x8*>(Bs + (sr + 64) * LDT + sc) = b1;
    __syncthreads();

    bf16x8 af[4], bfr[4];
    for (int m = 0; m < 4; m++)
      af[m] = __builtin_bit_cast(bf16x8,
        *reinterpret_cast<const s16x8*>(As + (wr*64 + m*16 + lo) * LDT + hi*8));
    for (int n = 0; n < 4; n++)
      bfr[n] = __builtin_bit_cast(bf16x8,
        *reinterpret_cast<const s16x8*>(Bs + (wc*64 + n*16 + lo) * LDT + hi*8));
    for (int m = 0; m < 4; m++)
      for (int n = 0; n < 4; n++)
        acc[m][n] = __builtin_amdgcn_mfma_f32_16x16x32_bf16(af[m], bfr[n], acc[m][n], 0, 0, 0);
    __syncthreads();
  }

  // epilogue: C/D layout col=lane&15, row=(lane>>4)*4+reg
  if (EPI == 0) {
    const int sec = col0 >> 10;   // 0=q,1=k,2=v (BN=128 divides 1024, no crossing)
    for (int m = 0; m < 4; m++) {
      int rbase = row0 + wr*64 + m*16 + hi*4;
      for (int n = 0; n < 4; n++) {
        int c  = col0 + wc*64 + n*16 + lo;
        int cc = c & 1023;
        int h  = cc >> 6, d = cc & 63;
        float bv = bias[c];
        for (int i = 0; i < 4; i++) {
          int r = rbase + i;
          int b = r >> 11, t = r & 2047;
          int bh = b * HH + h;
          unsigned short val = f2bf(acc[m][n][i] + bv);
          if (sec == 0)      qbuf [((size_t)bh * TT + t) * DD + d] = val;
          else if (sec == 1) kbuf [((size_t)bh * TT + t) * DD + d] = val;
          else               vtbuf[((size_t)bh * DD + d) * TT + t] = val;
        }
      }
    }
  } else {
    for (int m = 0; m < 4; m++) {
      int rbase = row0 + wr*64 + m*16 + hi*4;
      for (int n = 0; n < 4; n++) {
        int c = col0 + wc*64 + n*16 + lo;
        float bv = bias[c];
        for (int i = 0; i < 4; i++)
          outf[(size_t)(rbase + i) * CC + c] = acc[m][n][i] + bv;
      }
    }
  }
}

// ---------- flash attention (causal) ----------
// grid: (B*H, T/64); block 256 = 4 waves; wave w owns q rows [qb*64+16w, +16)
__global__ __launch_bounds__(256)
void attn_kernel(const unsigned short* __restrict__ qbuf,
                 const unsigned short* __restrict__ kbuf,
                 const unsigned short* __restrict__ vtbuf,
                 unsigned short* __restrict__ obuf)
{
  __shared__ unsigned short P[4][16 * 88];   // per-wave P tile, stride 176B (2-way banks)
  const int tid  = threadIdx.x;
  const int lane = tid & 63;
  const int w    = tid >> 6;
  const int lo   = lane & 15, hi = lane >> 4;
  const int bh   = blockIdx.x;
  const int qblk = blockIdx.y;
  const int qbase = qblk * 64 + w * 16;

  // Q A-frags (row = lane&15, k(d) = hi*8+j), held for the whole kernel
  const unsigned short* qp = qbuf + ((size_t)bh * TT + qbase + lo) * DD + hi * 8;
  bf16x8 aq0 = ld8(qp);
  bf16x8 aq1 = ld8(qp + 32);

  float mrow[4], lrow[4];
  f32x4 acc_o[4];
  for (int i = 0; i < 4; i++) { mrow[i] = -1e30f; lrow[i] = 0.f; }
  for (int f = 0; f < 4; f++)
    for (int j = 0; j < 4; j++) acc_o[f][j] = 0.f;

  unsigned short* Pw = &P[w][0];

  for (int kt = 0; kt <= qblk; ++kt) {
    const int kbase = kt * 64;
    // ---- S = Q K^T (16 q-rows x 64 keys) ----
    f32x4 s[4];
    for (int f = 0; f < 4; f++) for (int j = 0; j < 4; j++) s[f][j] = 0.f;
    for (int f = 0; f < 4; f++) {
      const unsigned short* kp = kbuf + ((size_t)bh * TT + kbase + f*16 + lo) * DD + hi * 8;
      bf16x8 b0 = ld8(kp);
      bf16x8 b1 = ld8(kp + 32);
      s[f] = __builtin_amdgcn_mfma_f32_16x16x32_bf16(aq0, b0, s[f], 0, 0, 0);
      s[f] = __builtin_amdgcn_mfma_f32_16x16x32_bf16(aq1, b1, s[f], 0, 0, 0);
    }
    // ---- scale + causal mask + row max ----
    const bool diag = (kt == qblk);
    float tm[4] = {-1e30f, -1e30f, -1e30f, -1e30f};
    for (int f = 0; f < 4; f++)
      for (int i = 0; i < 4; i++) {
        float v = s[f][i] * 0.125f;
        if (diag && (kbase + f*16 + lo > qbase + hi*4 + i)) v = -1e30f;
        s[f][i] = v;
        tm[i] = fmaxf(tm[i], v);
      }
    for (int xm = 1; xm < 16; xm <<= 1)
      for (int i = 0; i < 4; i++) tm[i] = fmaxf(tm[i], __shfl_xor(tm[i], xm));
    // ---- online softmax update, write P to LDS ----
    float rs[4];
    for (int i = 0; i < 4; i++) {
      float mn   = fmaxf(mrow[i], tm[i]);
      float corr = __expf(mrow[i] - mn);
      mrow[i] = mn;
      float r = 0.f;
      for (int f = 0; f < 4; f++) {
        float p = __expf(s[f][i] - mn);
        r += p;
        Pw[(hi*4 + i) * 88 + f*16 + lo] = f2bf(p);
      }
      rs[i] = r;
      lrow[i] *= corr;
      for (int f = 0; f < 4; f++) acc_o[f][i] *= corr;
    }
    for (int xm = 1; xm < 16; xm <<= 1)
      for (int i = 0; i < 4; i++) rs[i] += __shfl_xor(rs[i], xm);
    for (int i = 0; i < 4; i++) lrow[i] += rs[i];

    __syncthreads();   // intra-wave RAW safety for P (cheap insurance)

    // ---- O += P V ----
    bf16x8 pa0 = ld8(Pw + lo * 88 + hi * 8);        // keys 0..31
    bf16x8 pa1 = ld8(Pw + lo * 88 + 32 + hi * 8);   // keys 32..63
    for (int f = 0; f < 4; f++) {
      const unsigned short* vp = vtbuf + ((size_t)bh * DD + f*16 + lo) * TT + kbase + hi * 8;
      bf16x8 v0 = ld8(vp);
      bf16x8 v1 = ld8(vp + 32);
      acc_o[f] = __builtin_amdgcn_mfma_f32_16x16x32_bf16(pa0, v0, acc_o[f], 0, 0, 0);
      acc_o[f] = __builtin_amdgcn_mfma_f32_16x16x32_bf16(pa1, v1, acc_o[f], 0, 0, 0);
    }
  }

  // ---- normalize + write O as bf16 [B,T,H,D] = [B,T,C] ----
  const int b = bh >> 4, h = bh & 15;
  for (int f = 0; f < 4; f++)
    for (int i = 0; i < 4; i++) {
      int r = qbase + hi*4 + i;
      float v = acc_o[f][i] / lrow[i];
      obuf[((size_t)(b * TT + r)) * CC + h*64 + f*16 + lo] = f2bf(v);
    }
}

// ---------- launcher ----------
extern "C" void kernel_launch(void* const* d_in, const int* in_sizes, int n_in,
                              void* d_out, int out_size, void* d_ws, size_t ws_size,
                              hipStream_t stream) {
  const float* x     = (const float*)d_in[0];
  const float* Wqkv  = (const float*)d_in[1];
  const float* bqkv  = (const float*)d_in[2];
  const float* Wproj = (const float*)d_in[3];
  const float* bproj = (const float*)d_in[4];
  float* out = (float*)d_out;

  // workspace layout (bf16 elements). xb is dead after gemm1; obuf aliases it.
  unsigned short* ws  = (unsigned short*)d_ws;
  unsigned short* xb  = ws;                                  // [8192,1024]  (also obuf later)
  unsigned short* w1t = xb  + (size_t)MM * CC;               // [3072,1024]
  unsigned short* w2t = w1t + (size_t)3 * CC * CC;           // [1024,1024]
  unsigned short* qbf = w2t + (size_t)CC * CC;               // [B,H,T,D]
  unsigned short* kbf = qbf + (size_t)BB * HH * TT * DD;     // [B,H,T,D]
  unsigned short* vtb = kbf + (size_t)BB * HH * TT * DD;     // [B,H,D,T]
  unsigned short* obf = xb;                                  // alias: [B,T,C]

  cvt_f32_bf16<<<2048, 256, 0, stream>>>(x, xb, MM * CC);
  transpose_cvt<<<dim3(3*CC/32, CC/32), dim3(32, 8), 0, stream>>>(Wqkv, w1t, CC, 3*CC);
  transpose_cvt<<<dim3(CC/32,  CC/32), dim3(32, 8), 0, stream>>>(Wproj, w2t, CC, CC);

  gemm_bt<0><<<dim3(MM/BMT, 3*CC/BNT), 256, 0, stream>>>(xb, w1t, bqkv, CC,
                                                         qbf, kbf, vtb, nullptr);
  attn_kernel<<<dim3(BB*HH, TT/64), 256, 0, stream>>>(qbf, kbf, vtb, obf);
  gemm_bt<1><<<dim3(MM/BMT, CC/BNT), 256, 0, stream>>>(obf, w2t, bproj, CC,
                                                       nullptr, nullptr, nullptr, out);
}

// Round 2
// 371.335 us; speedup vs baseline: 1.2981x; 1.2981x over previous
//
#include <hip/hip_runtime.h>
#include <stdint.h>

// ---------- types / helpers ----------
typedef __bf16 bf16x8 __attribute__((ext_vector_type(8)));
typedef float  f32x4  __attribute__((ext_vector_type(4)));
typedef short  s16x8  __attribute__((ext_vector_type(8)));

__device__ __forceinline__ unsigned short f2bf(float f) {
  unsigned u = __builtin_bit_cast(unsigned, f);
  u += 0x7fffu + ((u >> 16) & 1u);          // RNE
  return (unsigned short)(u >> 16);
}

__device__ __forceinline__ bf16x8 ld8(const unsigned short* p) {
  return __builtin_bit_cast(bf16x8, *reinterpret_cast<const s16x8*>(p));
}

// ---------- problem constants ----------
#define BB 4
#define TT 2048
#define CC 1024
#define HH 16
#define DD 64
#define MM (BB*TT)        // 8192

// ---------- kernel 0: f32 -> bf16 convert ----------
__global__ __launch_bounds__(256) void cvt_f32_bf16(const float* __restrict__ in,
                                                    unsigned short* __restrict__ out, int n) {
  int idx = blockIdx.x * blockDim.x + threadIdx.x;
  int stride = gridDim.x * blockDim.x;
  for (int i = idx * 4; i < n; i += stride * 4) {
    float4 v = *reinterpret_cast<const float4*>(in + i);
    ushort4 o;
    o.x = f2bf(v.x); o.y = f2bf(v.y); o.z = f2bf(v.z); o.w = f2bf(v.w);
    *reinterpret_cast<ushort4*>(out + i) = o;
  }
}

// ---------- kernel 1: transpose + convert  out[n][k] = (bf16) in[k][n] ----------
__global__ __launch_bounds__(256) void transpose_cvt(const float* __restrict__ in,
                                                     unsigned short* __restrict__ out,
                                                     int K, int N) {
  __shared__ float tile[32][33];
  int kb = blockIdx.y * 32, nb = blockIdx.x * 32;
  int tx = threadIdx.x, ty = threadIdx.y;      // block (32,8)
  for (int i = 0; i < 4; i++)
    tile[ty + i*8][tx] = in[(size_t)(kb + ty + i*8) * N + nb + tx];
  __syncthreads();
  for (int i = 0; i < 4; i++)
    out[(size_t)(nb + ty + i*8) * K + kb + tx] = f2bf(tile[tx][ty + i*8]);
}

// ---------- GEMM: C[M,N] = A[M,K](bf16) * Bt[N,K](bf16) + bias ----------
#define BMT 128
#define BNT 128
#define BKT 32
#define LDT 56   // padded leading dim (stride 112 B -> 2-way banks, free)

template<int EPI>
__global__ __launch_bounds__(256)
void gemm_bt(const unsigned short* __restrict__ A, const unsigned short* __restrict__ Bt,
             const float* __restrict__ bias, int K,
             unsigned short* __restrict__ qbuf, unsigned short* __restrict__ kbuf,
             unsigned short* __restrict__ vtbuf, float* __restrict__ outf)
{
  __shared__ unsigned short As[BMT * LDT];
  __shared__ unsigned short Bs[BNT * LDT];
  const int tid  = threadIdx.x;
  const int lane = tid & 63;
  const int w    = tid >> 6;
  const int wr   = w >> 1, wc = w & 1;
  const int lo   = lane & 15, hi = lane >> 4;
  const int row0 = blockIdx.x * BMT, col0 = blockIdx.y * BNT;

  f32x4 acc[4][4];
  for (int m = 0; m < 4; m++)
    for (int n = 0; n < 4; n++)
      for (int j = 0; j < 4; j++) acc[m][n][j] = 0.f;

  const int sr = tid >> 2;         // 0..63
  const int sc = (tid & 3) * 8;    // 0,8,16,24

  for (int k0 = 0; k0 < K; k0 += BKT) {
    s16x8 a0 = *reinterpret_cast<const s16x8*>(A  + (size_t)(row0 + sr)      * K + k0 + sc);
    s16x8 a1 = *reinterpret_cast<const s16x8*>(A  + (size_t)(row0 + sr + 64) * K + k0 + sc);
    s16x8 b0 = *reinterpret_cast<const s16x8*>(Bt + (size_t)(col0 + sr)      * K + k0 + sc);
    s16x8 b1 = *reinterpret_cast<const s16x8*>(Bt + (size_t)(col0 + sr + 64) * K + k0 + sc);
    *reinterpret_cast<s16x8*>(As + sr        * LDT + sc) = a0;
    *reinterpret_cast<s16x8*>(As + (sr + 64) * LDT + sc) = a1;
    *reinterpret_cast<s16x8*>(Bs + sr        * LDT + sc) = b0;
    *reinterpret_cast<s16x8*>(Bs + (sr + 64) * LDT + sc) = b1;
    __syncthreads();

    bf16x8 af[4], bfr[4];
    for (int m = 0; m < 4; m++)
      af[m] = __builtin_bit_cast(bf16x8,
        *reinterpret_cast<const s16x8*>(As + (wr*64 + m*16 + lo) * LDT + hi*8));
    for (int n = 0; n < 4; n++)
      bfr[n] = __builtin_bit_cast(bf16x8,
        *reinterpret_cast<const s16x8*>(Bs + (wc*64 + n*16 + lo) * LDT + hi*8));
    for (int m = 0; m < 4; m++)
      for (int n = 0; n < 4; n++)
        acc[m][n] = __builtin_amdgcn_mfma_f32_16x16x32_bf16(af[m], bfr[n], acc[m][n], 0, 0, 0);
    __syncthreads();
  }

  if (EPI == 0) {
    const int sec = col0 >> 10;   // 0=q,1=k,2=v
    for (int m = 0; m < 4; m++) {
      int rbase = row0 + wr*64 + m*16 + hi*4;
      for (int n = 0; n < 4; n++) {
        int c  = col0 + wc*64 + n*16 + lo;
        int cc = c & 1023;
        int h  = cc >> 6, d = cc & 63;
        float bv = bias[c];
        for (int i = 0; i < 4; i++) {
          int r = rbase + i;
          int b = r >> 11, t = r & 2047;
          int bh = b * HH + h;
          unsigned short val = f2bf(acc[m][n][i] + bv);
          if (sec == 0)      qbuf [((size_t)bh * TT + t) * DD + d] = val;
          else if (sec == 1) kbuf [((size_t)bh * TT + t) * DD + d] = val;
          else               vtbuf[((size_t)bh * DD + d) * TT + t] = val;
        }
      }
    }
  } else {
    for (int m = 0; m < 4; m++) {
      int rbase = row0 + wr*64 + m*16 + hi*4;
      for (int n = 0; n < 4; n++) {
        int c = col0 + wc*64 + n*16 + lo;
        float bv = bias[c];
        for (int i = 0; i < 4; i++)
          outf[(size_t)(rbase + i) * CC + c] = acc[m][n][i] + bv;
      }
    }
  }
}

// ---------- flash attention v2 (causal) ----------
// grid: (B*H, T/128); block 256 = 4 waves; wave w owns 32 q rows as two
// independent 16-row streams (ILP: two QK->softmax->PV chains overlap).
// No __syncthreads: P tile is per-wave, intra-wave LDS RAW is handled by
// compiler-inserted lgkmcnt waits.
#define PLD 88   // P leading dim (stride 176 B)

__global__ __launch_bounds__(256)
void attn_kernel(const unsigned short* __restrict__ qbuf,
                 const unsigned short* __restrict__ kbuf,
                 const unsigned short* __restrict__ vtbuf,
                 unsigned short* __restrict__ obuf)
{
  __shared__ unsigned short P[4][32 * PLD];
  const int tid  = threadIdx.x;
  const int lane = tid & 63;
  const int w    = tid >> 6;
  const int lo   = lane & 15, hi = lane >> 4;
  const int bh   = blockIdx.x;
  const int qblk = gridDim.y - 1 - blockIdx.y;   // heavy-first
  const int qbase = qblk * 128 + w * 32;

  // Q A-frags for both streams (row = lane&15, d = hi*8+j)
  bf16x8 aq[2][2];
  #pragma unroll
  for (int st = 0; st < 2; st++) {
    const unsigned short* qp = qbuf + ((size_t)bh * TT + qbase + st*16 + lo) * DD + hi * 8;
    aq[st][0] = ld8(qp);
    aq[st][1] = ld8(qp + 32);
  }

  float mrow[2][4], lrow[2][4];
  f32x4 acc_o[2][4];
  #pragma unroll
  for (int st = 0; st < 2; st++)
    for (int i = 0; i < 4; i++) {
      mrow[st][i] = -1e30f; lrow[st][i] = 0.f;
      for (int f = 0; f < 4; f++) acc_o[st][f][i] = 0.f;
    }

  unsigned short* Pw = &P[w][0];
  const int nfull = qbase >> 6;   // tiles before the (single) diagonal tile

  for (int kt = 0; kt <= nfull; ++kt) {
    const int kbase = kt * 64;
    const bool diag = (kt == nfull);

    // ---- S = Q K^T for both streams ----
    f32x4 s[2][4];
    #pragma unroll
    for (int st = 0; st < 2; st++)
      for (int f = 0; f < 4; f++)
        for (int j = 0; j < 4; j++) s[st][f][j] = 0.f;

    __builtin_amdgcn_s_setprio(1);
    #pragma unroll
    for (int f = 0; f < 4; f++) {
      const unsigned short* kp = kbuf + ((size_t)bh * TT + kbase + f*16 + lo) * DD + hi * 8;
      bf16x8 b0 = ld8(kp);
      bf16x8 b1 = ld8(kp + 32);
      s[0][f] = __builtin_amdgcn_mfma_f32_16x16x32_bf16(aq[0][0], b0, s[0][f], 0, 0, 0);
      s[0][f] = __builtin_amdgcn_mfma_f32_16x16x32_bf16(aq[0][1], b1, s[0][f], 0, 0, 0);
      s[1][f] = __builtin_amdgcn_mfma_f32_16x16x32_bf16(aq[1][0], b0, s[1][f], 0, 0, 0);
      s[1][f] = __builtin_amdgcn_mfma_f32_16x16x32_bf16(aq[1][1], b1, s[1][f], 0, 0, 0);
    }
    __builtin_amdgcn_s_setprio(0);

    // ---- softmax per stream, write P to LDS ----
    #pragma unroll
    for (int st = 0; st < 2; st++) {
      const int rowoff = qbase + st*16 + hi*4;
      float tm[4] = {-1e30f, -1e30f, -1e30f, -1e30f};
      #pragma unroll
      for (int f = 0; f < 4; f++)
        for (int i = 0; i < 4; i++) {
          float v = s[st][f][i] * 0.125f;
          if (diag && (kbase + f*16 + lo > rowoff + i)) v = -1e30f;
          s[st][f][i] = v;
          tm[i] = fmaxf(tm[i], v);
        }
      #pragma unroll
      for (int xm = 1; xm < 16; xm <<= 1)
        for (int i = 0; i < 4; i++) tm[i] = fmaxf(tm[i], __shfl_xor(tm[i], xm));
      float rs[4];
      #pragma unroll
      for (int i = 0; i < 4; i++) {
        float mn   = fmaxf(mrow[st][i], tm[i]);
        float corr = __expf(mrow[st][i] - mn);
        mrow[st][i] = mn;
        float r = 0.f;
        #pragma unroll
        for (int f = 0; f < 4; f++) {
          float p = __expf(s[st][f][i] - mn);
          r += p;
          Pw[(st*16 + hi*4 + i) * PLD + f*16 + lo] = f2bf(p);
        }
        rs[i] = r;
        lrow[st][i] *= corr;
        #pragma unroll
        for (int f = 0; f < 4; f++) acc_o[st][f][i] *= corr;
      }
      #pragma unroll
      for (int xm = 1; xm < 16; xm <<= 1)
        for (int i = 0; i < 4; i++) rs[i] += __shfl_xor(rs[i], xm);
      for (int i = 0; i < 4; i++) lrow[st][i] += rs[i];
    }

    // ---- O += P V (both streams share V-frags) ----
    bf16x8 pa[2][2];
    #pragma unroll
    for (int st = 0; st < 2; st++) {
      pa[st][0] = ld8(Pw + (st*16 + lo) * PLD + hi * 8);        // keys 0..31
      pa[st][1] = ld8(Pw + (st*16 + lo) * PLD + 32 + hi * 8);   // keys 32..63
    }
    __builtin_amdgcn_s_setprio(1);
    #pragma unroll
    for (int f = 0; f < 4; f++) {
      const unsigned short* vp = vtbuf + ((size_t)bh * DD + f*16 + lo) * TT + kbase + hi * 8;
      bf16x8 v0 = ld8(vp);
      bf16x8 v1 = ld8(vp + 32);
      acc_o[0][f] = __builtin_amdgcn_mfma_f32_16x16x32_bf16(pa[0][0], v0, acc_o[0][f], 0, 0, 0);
      acc_o[0][f] = __builtin_amdgcn_mfma_f32_16x16x32_bf16(pa[0][1], v1, acc_o[0][f], 0, 0, 0);
      acc_o[1][f] = __builtin_amdgcn_mfma_f32_16x16x32_bf16(pa[1][0], v0, acc_o[1][f], 0, 0, 0);
      acc_o[1][f] = __builtin_amdgcn_mfma_f32_16x16x32_bf16(pa[1][1], v1, acc_o[1][f], 0, 0, 0);
    }
    __builtin_amdgcn_s_setprio(0);
  }

  // ---- normalize + write O as bf16 [B,T,C] ----
  const int b = bh >> 4, h = bh & 15;
  #pragma unroll
  for (int st = 0; st < 2; st++)
    for (int f = 0; f < 4; f++)
      for (int i = 0; i < 4; i++) {
        int r = qbase + st*16 + hi*4 + i;
        float v = acc_o[st][f][i] / lrow[st][i];
        obuf[((size_t)(b * TT + r)) * CC + h*64 + f*16 + lo] = f2bf(v);
      }
}

// ---------- launcher ----------
extern "C" void kernel_launch(void* const* d_in, const int* in_sizes, int n_in,
                              void* d_out, int out_size, void* d_ws, size_t ws_size,
                              hipStream_t stream) {
  const float* x     = (const float*)d_in[0];
  const float* Wqkv  = (const float*)d_in[1];
  const float* bqkv  = (const float*)d_in[2];
  const float* Wproj = (const float*)d_in[3];
  const float* bproj = (const float*)d_in[4];
  float* out = (float*)d_out;

  unsigned short* ws  = (unsigned short*)d_ws;
  unsigned short* xb  = ws;                                  // [8192,1024]  (also obuf later)
  unsigned short* w1t = xb  + (size_t)MM * CC;               // [3072,1024]
  unsigned short* w2t = w1t + (size_t)3 * CC * CC;           // [1024,1024]
  unsigned short* qbf = w2t + (size_t)CC * CC;               // [B,H,T,D]
  unsigned short* kbf = qbf + (size_t)BB * HH * TT * DD;     // [B,H,T,D]
  unsigned short* vtb = kbf + (size_t)BB * HH * TT * DD;     // [B,H,D,T]
  unsigned short* obf = xb;                                  // alias: [B,T,C]

  cvt_f32_bf16<<<2048, 256, 0, stream>>>(x, xb, MM * CC);
  transpose_cvt<<<dim3(3*CC/32, CC/32), dim3(32, 8), 0, stream>>>(Wqkv, w1t, CC, 3*CC);
  transpose_cvt<<<dim3(CC/32,  CC/32), dim3(32, 8), 0, stream>>>(Wproj, w2t, CC, CC);

  gemm_bt<0><<<dim3(MM/BMT, 3*CC/BNT), 256, 0, stream>>>(xb, w1t, bqkv, CC,
                                                         qbf, kbf, vtb, nullptr);
  attn_kernel<<<dim3(BB*HH, TT/128), 256, 0, stream>>>(qbf, kbf, vtb, obf);
  gemm_bt<1><<<dim3(MM/BMT, CC/BNT), 256, 0, stream>>>(obf, w2t, bproj, CC,
                                                       nullptr, nullptr, nullptr, out);
}